// Round 1
// baseline (593.992 us; speedup 1.0000x reference)
//
#include <hip/hip_runtime.h>

// Problem constants (match reference)
constexpr int B_    = 4;
constexpr int V_    = 80000;
constexpr int P_    = 20;
constexpr int COUT  = 64;
constexpr int NX_   = 640;
constexpr int NY_   = 640;
constexpr int NYX   = NX_ * NY_;          // 409600
constexpr float BEV = 100.0f;
constexpr float VXc = BEV / NX_;           // 0.15625
constexpr float VYc = BEV / NY_;
constexpr float XOFF = VXc * 0.5f - BEV * 0.5f;   // -49.921875
constexpr float YOFF = VYc * 0.5f - BEV * 0.5f;
constexpr float EPS  = 0.001f;

// Pass 1: one wave (64 lanes) per pillar; lane = output channel.
// Writes pillar features (V x 64) to ws and scatters pillar id into idxmap.
__global__ __launch_bounds__(256) void pillar_feat_kernel(
    const float* __restrict__ voxels,      // (V, P, 4)
    const int*   __restrict__ num_points,  // (V,)
    const int*   __restrict__ coors,       // (V, 4)  [b, 0, y, x]
    const float* __restrict__ W,           // (9, 64)
    const float* __restrict__ gamma_,      // (64,)
    const float* __restrict__ beta_,       // (64,)
    const float* __restrict__ rmean,       // (64,)
    const float* __restrict__ rvar,        // (64,)
    float* __restrict__ feat,              // (V, 64) out
    int*   __restrict__ idxmap)            // (B*NYX,) out (pre-set to -1)
{
    const int v = blockIdx.x * 4 + (threadIdx.x >> 6);   // pillar (wave-uniform)
    const int c = threadIdx.x & 63;                       // channel (lane)
    if (v >= V_) return;

    int n = num_points[v];
    n = n < 1 ? 1 : (n > P_ ? P_ : n);

    const int cb  = coors[4 * v + 0];
    const int cyi = coors[4 * v + 2];
    const int cxi = coors[4 * v + 3];

    // Fold BN into weights/bias: h' = feats . (W*scale) + bias
    const float scale = gamma_[c] * rsqrtf(rvar[c] + EPS);
    const float bias  = beta_[c] - rmean[c] * scale;
    float w[9];
    #pragma unroll
    for (int i = 0; i < 9; ++i) w[i] = W[i * COUT + c] * scale;

    const float4* __restrict__ pv =
        (const float4*)(voxels + (size_t)v * (P_ * 4));

    // Mean of xyz over valid points (wave-uniform loads, broadcast by HW)
    float sx = 0.f, sy = 0.f, sz = 0.f;
    for (int p = 0; p < n; ++p) {
        float4 q = pv[p];
        sx += q.x; sy += q.y; sz += q.z;
    }
    const float inv = 1.0f / (float)n;
    const float mx = sx * inv, my = sy * inv, mz = sz * inv;
    const float ccx = (float)cxi * VXc + XOFF;
    const float ccy = (float)cyi * VYc + YOFF;

    float m = -3.4e38f;
    for (int p = 0; p < n; ++p) {
        float4 q = pv[p];
        float h = bias;
        h += q.x * w[0];
        h += q.y * w[1];
        h += q.z * w[2];
        h += q.w * w[3];
        h += (q.x - mx)  * w[4];
        h += (q.y - my)  * w[5];
        h += (q.z - mz)  * w[6];
        h += (q.x - ccx) * w[7];
        h += (q.y - ccy) * w[8];
        m = fmaxf(m, h);
    }
    // Invalid rows have all-zero features -> h = bias; they participate in max
    if (n < P_) m = fmaxf(m, bias);

    feat[(size_t)v * COUT + c] = fmaxf(m, 0.0f);   // relu after max (monotone)

    if (c == 0) idxmap[cb * NYX + cyi * NX_ + cxi] = v;
}

// Pass 2: gather. One thread per canvas cell (b,y,x); loops all 64 channels.
// All stores are unconditional -> fully coalesced 256 B/wave per plane.
__global__ __launch_bounds__(256) void scatter_kernel(
    const float* __restrict__ feat,     // (V, 64)
    const int*   __restrict__ idxmap,   // (B*NYX,)
    float* __restrict__ canvas,         // (B, 64, NY, NX)
    float* __restrict__ occ)            // (B, 1, NY, NX)
{
    const int cell = blockIdx.x * blockDim.x + threadIdx.x;
    if (cell >= B_ * NYX) return;

    const int idx = idxmap[cell];
    const int b   = cell / NYX;
    const int rem = cell - b * NYX;

    occ[cell] = (idx >= 0) ? 1.0f : 0.0f;

    const size_t base = (size_t)b * COUT * NYX + (size_t)rem;
    const float4* __restrict__ f4 =
        (idx >= 0) ? (const float4*)(feat + (size_t)idx * COUT) : nullptr;

    #pragma unroll
    for (int cg = 0; cg < 16; ++cg) {
        float4 q = make_float4(0.f, 0.f, 0.f, 0.f);
        if (idx >= 0) q = f4[cg];
        canvas[base + (size_t)(4 * cg + 0) * NYX] = q.x;
        canvas[base + (size_t)(4 * cg + 1) * NYX] = q.y;
        canvas[base + (size_t)(4 * cg + 2) * NYX] = q.z;
        canvas[base + (size_t)(4 * cg + 3) * NYX] = q.w;
    }
}

extern "C" void kernel_launch(void* const* d_in, const int* in_sizes, int n_in,
                              void* d_out, int out_size, void* d_ws, size_t ws_size,
                              hipStream_t stream) {
    const float* voxels     = (const float*)d_in[0];
    const int*   num_points = (const int*)  d_in[1];
    const int*   coors      = (const int*)  d_in[2];
    const float* W          = (const float*)d_in[3];
    const float* gamma_     = (const float*)d_in[4];
    const float* beta_      = (const float*)d_in[5];
    const float* rmean      = (const float*)d_in[6];
    const float* rvar       = (const float*)d_in[7];

    float* canvas = (float*)d_out;                         // (B,64,NY,NX)
    float* occ    = (float*)d_out + (size_t)B_ * COUT * NYX;

    float* feat   = (float*)d_ws;                          // V*64 floats = 20.5 MB
    int*   idxmap = (int*)((char*)d_ws + (size_t)V_ * COUT * sizeof(float)); // 6.55 MB

    // idxmap = -1 everywhere (0xFF bytes)
    hipMemsetAsync(idxmap, 0xFF, (size_t)B_ * NYX * sizeof(int), stream);

    pillar_feat_kernel<<<(V_ + 3) / 4, 256, 0, stream>>>(
        voxels, num_points, coors, W, gamma_, beta_, rmean, rvar, feat, idxmap);

    scatter_kernel<<<(B_ * NYX + 255) / 256, 256, 0, stream>>>(
        feat, idxmap, canvas, occ);
}

// Round 3
// 557.653 us; speedup vs baseline: 1.0652x; 1.0652x over previous
//
#include <hip/hip_runtime.h>

// Problem constants (match reference)
constexpr int B_    = 4;
constexpr int V_    = 80000;
constexpr int P_    = 20;
constexpr int COUT  = 64;
constexpr int NX_   = 640;
constexpr int NY_   = 640;
constexpr int NYX   = NX_ * NY_;          // 409600 (divisible by 4)
constexpr float BEV = 100.0f;
constexpr float VXc = BEV / NX_;           // 0.15625
constexpr float VYc = BEV / NY_;
constexpr float XOFF = VXc * 0.5f - BEV * 0.5f;   // -49.921875
constexpr float YOFF = VYc * 0.5f - BEV * 0.5f;
constexpr float EPS  = 0.001f;

// Native vector type usable with __builtin_nontemporal_store
typedef float  vf4 __attribute__((ext_vector_type(4)));

// Pass 1: one wave (64 lanes) per pillar; lane = output channel.
// Writes pillar features (V x 64) to ws and scatters pillar id into idxmap.
__global__ __launch_bounds__(256) void pillar_feat_kernel(
    const float* __restrict__ voxels,      // (V, P, 4)
    const int*   __restrict__ num_points,  // (V,)
    const int*   __restrict__ coors,       // (V, 4)  [b, 0, y, x]
    const float* __restrict__ W,           // (9, 64)
    const float* __restrict__ gamma_,      // (64,)
    const float* __restrict__ beta_,       // (64,)
    const float* __restrict__ rmean,       // (64,)
    const float* __restrict__ rvar,        // (64,)
    float* __restrict__ feat,              // (V, 64) out
    int*   __restrict__ idxmap)            // (B*NYX,) out (pre-set to -1)
{
    const int v = blockIdx.x * 4 + (threadIdx.x >> 6);   // pillar (wave-uniform)
    const int c = threadIdx.x & 63;                       // channel (lane)
    if (v >= V_) return;

    int n = num_points[v];
    n = n < 1 ? 1 : (n > P_ ? P_ : n);

    const int cb  = coors[4 * v + 0];
    const int cyi = coors[4 * v + 2];
    const int cxi = coors[4 * v + 3];

    // Fold BN into weights/bias: h' = feats . (W*scale) + bias
    const float scale = gamma_[c] * rsqrtf(rvar[c] + EPS);
    const float bias  = beta_[c] - rmean[c] * scale;
    float w[9];
    #pragma unroll
    for (int i = 0; i < 9; ++i) w[i] = W[i * COUT + c] * scale;

    const float4* __restrict__ pv =
        (const float4*)(voxels + (size_t)v * (P_ * 4));

    // Mean of xyz over valid points (wave-uniform loads, broadcast by HW)
    float sx = 0.f, sy = 0.f, sz = 0.f;
    for (int p = 0; p < n; ++p) {
        float4 q = pv[p];
        sx += q.x; sy += q.y; sz += q.z;
    }
    const float inv = 1.0f / (float)n;
    const float mx = sx * inv, my = sy * inv, mz = sz * inv;
    const float ccx = (float)cxi * VXc + XOFF;
    const float ccy = (float)cyi * VYc + YOFF;

    float m = -3.4e38f;
    for (int p = 0; p < n; ++p) {
        float4 q = pv[p];
        float h = bias;
        h += q.x * w[0];
        h += q.y * w[1];
        h += q.z * w[2];
        h += q.w * w[3];
        h += (q.x - mx)  * w[4];
        h += (q.y - my)  * w[5];
        h += (q.z - mz)  * w[6];
        h += (q.x - ccx) * w[7];
        h += (q.y - ccy) * w[8];
        m = fmaxf(m, h);
    }
    // Invalid rows have all-zero features -> h = bias; they participate in max
    if (n < P_) m = fmaxf(m, bias);

    feat[(size_t)v * COUT + c] = fmaxf(m, 0.0f);   // relu after max (monotone)

    if (c == 0) idxmap[cb * NYX + cyi * NX_ + cxi] = v;
}

// Pass 2: gather. Each thread owns 4 consecutive x-cells x all 64 channels.
// All canvas/occ stores are float4 (1 KB/wave per instruction), nontemporal.
__global__ __launch_bounds__(256) void scatter_kernel(
    const float* __restrict__ feat,     // (V, 64)
    const int*   __restrict__ idxmap,   // (B*NYX,)
    float* __restrict__ canvas,         // (B, 64, NY, NX)
    float* __restrict__ occ)            // (B, 1, NY, NX)
{
    const int t = blockIdx.x * blockDim.x + threadIdx.x;   // cell-group id
    if (t >= (B_ * NYX) / 4) return;

    const int4 id = ((const int4*)idxmap)[t];
    const int cell0 = t * 4;
    const int b   = cell0 / NYX;
    const int rem = cell0 - b * NYX;

    // occupancy plane (4 cells per store)
    vf4 o = { id.x >= 0 ? 1.f : 0.f,
              id.y >= 0 ? 1.f : 0.f,
              id.z >= 0 ? 1.f : 0.f,
              id.w >= 0 ? 1.f : 0.f };
    __builtin_nontemporal_store(o, (vf4*)(occ + cell0));

    const float4* __restrict__ f4 = (const float4*)feat;   // (V, 16) float4
    const size_t base = (size_t)b * COUT * NYX + (size_t)rem;

    #pragma unroll
    for (int cg = 0; cg < 16; ++cg) {
        float4 a0 = make_float4(0.f, 0.f, 0.f, 0.f);
        float4 a1 = a0, a2 = a0, a3 = a0;
        if (id.x >= 0) a0 = f4[(size_t)id.x * 16 + cg];
        if (id.y >= 0) a1 = f4[(size_t)id.y * 16 + cg];
        if (id.z >= 0) a2 = f4[(size_t)id.z * 16 + cg];
        if (id.w >= 0) a3 = f4[(size_t)id.w * 16 + cg];
        // transpose 4x4: s_k = channel (4*cg+k) values for the 4 cells
        vf4 s0 = { a0.x, a1.x, a2.x, a3.x };
        vf4 s1 = { a0.y, a1.y, a2.y, a3.y };
        vf4 s2 = { a0.z, a1.z, a2.z, a3.z };
        vf4 s3 = { a0.w, a1.w, a2.w, a3.w };
        float* p0 = canvas + base + (size_t)(4 * cg + 0) * NYX;
        __builtin_nontemporal_store(s0, (vf4*)p0);
        __builtin_nontemporal_store(s1, (vf4*)(p0 + NYX));
        __builtin_nontemporal_store(s2, (vf4*)(p0 + 2 * NYX));
        __builtin_nontemporal_store(s3, (vf4*)(p0 + 3 * NYX));
    }
}

extern "C" void kernel_launch(void* const* d_in, const int* in_sizes, int n_in,
                              void* d_out, int out_size, void* d_ws, size_t ws_size,
                              hipStream_t stream) {
    const float* voxels     = (const float*)d_in[0];
    const int*   num_points = (const int*)  d_in[1];
    const int*   coors      = (const int*)  d_in[2];
    const float* W          = (const float*)d_in[3];
    const float* gamma_     = (const float*)d_in[4];
    const float* beta_      = (const float*)d_in[5];
    const float* rmean      = (const float*)d_in[6];
    const float* rvar       = (const float*)d_in[7];

    float* canvas = (float*)d_out;                         // (B,64,NY,NX)
    float* occ    = (float*)d_out + (size_t)B_ * COUT * NYX;

    float* feat   = (float*)d_ws;                          // V*64 floats = 20.5 MB
    int*   idxmap = (int*)((char*)d_ws + (size_t)V_ * COUT * sizeof(float)); // 6.55 MB

    // idxmap = -1 everywhere (0xFF bytes)
    (void)hipMemsetAsync(idxmap, 0xFF, (size_t)B_ * NYX * sizeof(int), stream);

    pillar_feat_kernel<<<(V_ + 3) / 4, 256, 0, stream>>>(
        voxels, num_points, coors, W, gamma_, beta_, rmean, rvar, feat, idxmap);

    scatter_kernel<<<(B_ * NYX / 4 + 255) / 256, 256, 0, stream>>>(
        feat, idxmap, canvas, occ);
}

// Round 4
// 512.988 us; speedup vs baseline: 1.1579x; 1.0871x over previous
//
#include <hip/hip_runtime.h>

// Problem constants (match reference)
constexpr int B_    = 4;
constexpr int V_    = 80000;
constexpr int P_    = 20;
constexpr int COUT  = 64;
constexpr int NX_   = 640;
constexpr int NY_   = 640;
constexpr int NYX   = NX_ * NY_;          // 409600 (divisible by 4)
constexpr float BEV = 100.0f;
constexpr float VXc = BEV / NX_;           // 0.15625
constexpr float VYc = BEV / NY_;
constexpr float XOFF = VXc * 0.5f - BEV * 0.5f;   // -49.921875
constexpr float YOFF = VYc * 0.5f - BEV * 0.5f;
constexpr float EPS  = 0.001f;

// Native vector type usable with __builtin_nontemporal_store
typedef float  vf4 __attribute__((ext_vector_type(4)));

// Pass 1: one wave (64 lanes) per pillar; lane = output channel.
// Algebraic collapse: feats.W = x*(w0+w4+w7) + y*(w1+w5+w8) + z*(w2+w6)
//                             + i*w3 + (bias - mean.w456 - center.w78)
// The mean enters only the constant term, so max over points commutes with
// it -> single fused loop (5 VALU/point instead of ~15).
__global__ __launch_bounds__(256) void pillar_feat_kernel(
    const float* __restrict__ voxels,      // (V, P, 4)
    const int*   __restrict__ num_points,  // (V,)
    const int*   __restrict__ coors,       // (V, 4)  [b, 0, y, x]
    const float* __restrict__ W,           // (9, 64)
    const float* __restrict__ gamma_,      // (64,)
    const float* __restrict__ beta_,       // (64,)
    const float* __restrict__ rmean,       // (64,)
    const float* __restrict__ rvar,        // (64,)
    float* __restrict__ feat,              // (V, 64) out
    int*   __restrict__ idxmap)            // (B*NYX,) out (NOT pre-cleared)
{
    const int v = blockIdx.x * 4 + (threadIdx.x >> 6);   // pillar (wave-uniform)
    const int c = threadIdx.x & 63;                       // channel (lane)
    if (v >= V_) return;

    int n = num_points[v];
    n = n < 1 ? 1 : (n > P_ ? P_ : n);

    const int4 co = ((const int4*)coors)[v];
    const int cb = co.x, cyi = co.z, cxi = co.w;

    // Fold BN into weights/bias: h' = feats . (W*scale) + bias
    const float scale = gamma_[c] * rsqrtf(rvar[c] + EPS);
    const float bias  = beta_[c] - rmean[c] * scale;
    float w[9];
    #pragma unroll
    for (int i = 0; i < 9; ++i) w[i] = W[i * COUT + c] * scale;

    const float wcx = w[0] + w[4] + w[7];
    const float wcy = w[1] + w[5] + w[8];
    const float wcz = w[2] + w[6];
    const float wcw = w[3];

    const float4* __restrict__ pv =
        (const float4*)(voxels + (size_t)v * (P_ * 4));

    float sx = 0.f, sy = 0.f, sz = 0.f;
    float dmax = -3.4e38f;
    for (int p = 0; p < n; ++p) {
        float4 q = pv[p];        // wave-uniform load, HW broadcast
        sx += q.x; sy += q.y; sz += q.z;
        float d = q.x * wcx + q.y * wcy + q.z * wcz + q.w * wcw;
        dmax = fmaxf(dmax, d);
    }
    const float inv = 1.0f / (float)n;
    const float ccx = (float)cxi * VXc + XOFF;
    const float ccy = (float)cyi * VYc + YOFF;
    const float btot = bias - (sx * inv) * w[4] - (sy * inv) * w[5]
                            - (sz * inv) * w[6] - ccx * w[7] - ccy * w[8];

    float m = dmax + btot;
    // Invalid rows have all-zero features -> h = bias; they participate in max
    if (n < P_) m = fmaxf(m, bias);

    feat[(size_t)v * COUT + c] = fmaxf(m, 0.0f);   // relu after max (monotone)

    if (c == 0) idxmap[cb * NYX + cyi * NX_ + cxi] = v;
}

// Pass 2: gather. Each thread owns 4 consecutive x-cells x all 64 channels.
// idxmap is NOT pre-cleared: a candidate idx is accepted only if it is in
// range AND coors[idx] maps back to exactly this cell. Garbage is rejected;
// a coincidental in-range value that maps here IS the true occupant (the
// pillar kernel wrote that same value), so the result is identical.
__global__ __launch_bounds__(256) void scatter_kernel(
    const float* __restrict__ feat,     // (V, 64)
    const int*   __restrict__ idxmap,   // (B*NYX,)
    const int*   __restrict__ coors,    // (V, 4)
    float* __restrict__ canvas,         // (B, 64, NY, NX)
    float* __restrict__ occ)            // (B, 1, NY, NX)
{
    const int t = blockIdx.x * blockDim.x + threadIdx.x;   // cell-group id
    if (t >= (B_ * NYX) / 4) return;

    int4 id = ((const int4*)idxmap)[t];
    const int cell0 = t * 4;
    const int b   = cell0 / NYX;
    const int rem = cell0 - b * NYX;

    const int4* __restrict__ co4 = (const int4*)coors;
    auto check = [&](int idx, int cell) -> int {
        if (idx < 0 || idx >= V_) return -1;
        int4 co = co4[idx];
        return (co.x * NYX + co.z * NX_ + co.w == cell) ? idx : -1;
    };
    id.x = check(id.x, cell0 + 0);
    id.y = check(id.y, cell0 + 1);
    id.z = check(id.z, cell0 + 2);
    id.w = check(id.w, cell0 + 3);

    // occupancy plane (4 cells per store)
    vf4 o = { id.x >= 0 ? 1.f : 0.f,
              id.y >= 0 ? 1.f : 0.f,
              id.z >= 0 ? 1.f : 0.f,
              id.w >= 0 ? 1.f : 0.f };
    __builtin_nontemporal_store(o, (vf4*)(occ + cell0));

    const float4* __restrict__ f4 = (const float4*)feat;   // (V, 16) float4
    const size_t base = (size_t)b * COUT * NYX + (size_t)rem;

    #pragma unroll
    for (int cg = 0; cg < 16; ++cg) {
        float4 a0 = make_float4(0.f, 0.f, 0.f, 0.f);
        float4 a1 = a0, a2 = a0, a3 = a0;
        if (id.x >= 0) a0 = f4[(size_t)id.x * 16 + cg];
        if (id.y >= 0) a1 = f4[(size_t)id.y * 16 + cg];
        if (id.z >= 0) a2 = f4[(size_t)id.z * 16 + cg];
        if (id.w >= 0) a3 = f4[(size_t)id.w * 16 + cg];
        // transpose 4x4: s_k = channel (4*cg+k) values for the 4 cells
        vf4 s0 = { a0.x, a1.x, a2.x, a3.x };
        vf4 s1 = { a0.y, a1.y, a2.y, a3.y };
        vf4 s2 = { a0.z, a1.z, a2.z, a3.z };
        vf4 s3 = { a0.w, a1.w, a2.w, a3.w };
        float* p0 = canvas + base + (size_t)(4 * cg + 0) * NYX;
        __builtin_nontemporal_store(s0, (vf4*)p0);
        __builtin_nontemporal_store(s1, (vf4*)(p0 + NYX));
        __builtin_nontemporal_store(s2, (vf4*)(p0 + 2 * NYX));
        __builtin_nontemporal_store(s3, (vf4*)(p0 + 3 * NYX));
    }
}

extern "C" void kernel_launch(void* const* d_in, const int* in_sizes, int n_in,
                              void* d_out, int out_size, void* d_ws, size_t ws_size,
                              hipStream_t stream) {
    const float* voxels     = (const float*)d_in[0];
    const int*   num_points = (const int*)  d_in[1];
    const int*   coors      = (const int*)  d_in[2];
    const float* W          = (const float*)d_in[3];
    const float* gamma_     = (const float*)d_in[4];
    const float* beta_      = (const float*)d_in[5];
    const float* rmean      = (const float*)d_in[6];
    const float* rvar       = (const float*)d_in[7];

    float* canvas = (float*)d_out;                         // (B,64,NY,NX)
    float* occ    = (float*)d_out + (size_t)B_ * COUT * NYX;

    float* feat   = (float*)d_ws;                          // V*64 floats = 20.5 MB
    int*   idxmap = (int*)((char*)d_ws + (size_t)V_ * COUT * sizeof(float)); // 6.55 MB

    pillar_feat_kernel<<<(V_ + 3) / 4, 256, 0, stream>>>(
        voxels, num_points, coors, W, gamma_, beta_, rmean, rvar, feat, idxmap);

    scatter_kernel<<<(B_ * NYX / 4 + 255) / 256, 256, 0, stream>>>(
        feat, idxmap, coors, canvas, occ);
}